// Round 11
// baseline (627.704 us; speedup 1.0000x reference)
//
#include <hip/hip_runtime.h>
#include <math.h>

#define H      300
#define NLEAF  4096

__device__ __forceinline__ float sigmoidf_(float x) { return 1.0f / (1.0f + expf(-x)); }

// Load next 8 weight rows (2 consecutive cols) from wp, advance wp.
__device__ __forceinline__ void ldw8(const float*& wp, float2* w)
{
    #pragma unroll
    for (int i = 0; i < 8; ++i) w[i] = *(const float2*)&wp[i * H];
    wp += 8 * H;
}

// 8 k-steps x 2 cols of FMA for NN nodes starting at X row jbase.
template<int NN, int XW>
__device__ __forceinline__ void fma8(const float2* w, const float (*X)[XW],
                                     int jbase, int d, float* a0, float* a1)
{
    #pragma unroll
    for (int j = 0; j < NN; ++j) {
        float4 xlo = *(const float4*)&X[jbase + j][d];
        float4 xhi = *(const float4*)&X[jbase + j][d + 4];
        a0[j] = fmaf(xlo.x, w[0].x, a0[j]); a1[j] = fmaf(xlo.x, w[0].y, a1[j]);
        a0[j] = fmaf(xlo.y, w[1].x, a0[j]); a1[j] = fmaf(xlo.y, w[1].y, a1[j]);
        a0[j] = fmaf(xlo.z, w[2].x, a0[j]); a1[j] = fmaf(xlo.z, w[2].y, a1[j]);
        a0[j] = fmaf(xlo.w, w[3].x, a0[j]); a1[j] = fmaf(xlo.w, w[3].y, a1[j]);
        a0[j] = fmaf(xhi.x, w[4].x, a0[j]); a1[j] = fmaf(xhi.x, w[4].y, a1[j]);
        a0[j] = fmaf(xhi.y, w[5].x, a0[j]); a1[j] = fmaf(xhi.y, w[5].y, a1[j]);
        a0[j] = fmaf(xhi.z, w[6].x, a0[j]); a1[j] = fmaf(xhi.z, w[6].y, a1[j]);
        a0[j] = fmaf(xhi.w, w[7].x, a0[j]); a1[j] = fmaf(xhi.w, w[7].y, a1[j]);
    }
}

// Depth-4 software-pipelined GEMM over NCH chunks of 8 K-rows (R4-proven).
template<int NCH, int NN, int XW>
__device__ __forceinline__ void gemm_pipe(const float* wp, const float (*X)[XW],
                                          int jbase, float* a0, float* a1)
{
    float2 w0[8], w1[8], w2[8], w3[8];
    ldw8(wp, w0); ldw8(wp, w1); ldw8(wp, w2);
    int d = 0;
    constexpr int IT = (NCH - 3) / 4;
    constexpr int L  = (NCH - 3) - 4 * IT;
    for (int it = 0; it < IT; ++it) {
        ldw8(wp, w3); fma8<NN, XW>(w0, X, jbase, d,      a0, a1);
        ldw8(wp, w0); fma8<NN, XW>(w1, X, jbase, d + 8,  a0, a1);
        ldw8(wp, w1); fma8<NN, XW>(w2, X, jbase, d + 16, a0, a1);
        ldw8(wp, w2); fma8<NN, XW>(w3, X, jbase, d + 24, a0, a1);
        d += 32;
    }
    if constexpr (L == 0) {
        fma8<NN, XW>(w0, X, jbase, d,      a0, a1);
        fma8<NN, XW>(w1, X, jbase, d + 8,  a0, a1);
        fma8<NN, XW>(w2, X, jbase, d + 16, a0, a1);
    } else if constexpr (L == 1) {
        ldw8(wp, w3);
        fma8<NN, XW>(w0, X, jbase, d,      a0, a1);
        fma8<NN, XW>(w1, X, jbase, d + 8,  a0, a1);
        fma8<NN, XW>(w2, X, jbase, d + 16, a0, a1);
        fma8<NN, XW>(w3, X, jbase, d + 24, a0, a1);
    } else if constexpr (L == 2) {
        ldw8(wp, w3); fma8<NN, XW>(w0, X, jbase, d,      a0, a1);
        ldw8(wp, w0); fma8<NN, XW>(w1, X, jbase, d + 8,  a0, a1);
        fma8<NN, XW>(w2, X, jbase, d + 16, a0, a1);
        fma8<NN, XW>(w3, X, jbase, d + 24, a0, a1);
        fma8<NN, XW>(w0, X, jbase, d + 32, a0, a1);
    } else {
        ldw8(wp, w3); fma8<NN, XW>(w0, X, jbase, d,      a0, a1);
        ldw8(wp, w0); fma8<NN, XW>(w1, X, jbase, d + 8,  a0, a1);
        ldw8(wp, w1); fma8<NN, XW>(w2, X, jbase, d + 16, a0, a1);
        fma8<NN, XW>(w3, X, jbase, d + 24, a0, a1);
        fma8<NN, XW>(w0, X, jbase, d + 32, a0, a1);
        fma8<NN, XW>(w1, X, jbase, d + 40, a0, a1);
    }
}

// tag_r[t][k] = br[k] + sum_j tag_table[t][j] * Wr[300+j][k]   (likewise tag_z)
__global__ __launch_bounds__(320) void tag_kernel(
    const float* __restrict__ tag_table,
    const float* __restrict__ Wr, const float* __restrict__ br,
    const float* __restrict__ Wz, const float* __restrict__ bz,
    float* __restrict__ tag_r, float* __restrict__ tag_z)
{
    int t = blockIdx.x;
    int k = threadIdx.x;
    __shared__ float te[50];
    if (k < 50) te[k] = tag_table[t * 50 + k];
    __syncthreads();
    if (k < H) {
        float ar = br[k], az = bz[k];
        #pragma unroll 10
        for (int j = 0; j < 50; ++j) {
            float tv = te[j];
            ar = fmaf(tv, Wr[(H + j) * H + k], ar);
            az = fmaf(tv, Wz[(H + j) * H + k], az);
        }
        tag_r[t * H + k] = ar;
        tag_z[t * H + k] = az;
    }
}

// Leaf, 640 threads, 16 nodes: waves 0-4 -> nodes 0-7, waves 5-9 -> nodes 8-15.
// lh=rh=0 => r unused; h=(1-z)*u. K padded 300->304; X pad zeroed (extra W rows
// are valid memory x 0).
__global__ __launch_bounds__(640, 3) void leaf16_k(
    const int* __restrict__ word_ids, const int* __restrict__ tag_ids,
    const float* __restrict__ word_table,
    const float* __restrict__ Wz, const float* __restrict__ Wu,
    const float* __restrict__ bu, const float* __restrict__ tag_z,
    float* __restrict__ out)
{
    __shared__ float X[16][304];       // [300..303] zeroed
    __shared__ float exZ[2][300][8];   // z published by z-threads per half
    int node0 = blockIdx.x * 16;
    int tid = threadIdx.x;

    for (int idx = tid; idx < 16 * 76; idx += 640) {
        int j = idx / 76, q = idx - j * 76;
        if (q < 75)
            *(float4*)&X[j][q * 4] =
                *(const float4*)&word_table[(long)word_ids[node0 + j] * H + q * 4];
        else
            *(float4*)&X[j][300] = make_float4(0.f, 0.f, 0.f, 0.f);
    }
    __syncthreads();

    int hb = tid / 320;                 // node half
    int tt = tid - hb * 320;
    bool act = (tt < 300);
    int g = (tt >= 150);                // 0 = z, 1 = u
    int c0 = 2 * (tt - 150 * g);
    int jA = 8 * hb;

    float acc0[8], acc1[8];
    if (act) {
        #pragma unroll
        for (int j = 0; j < 8; ++j) { acc0[j] = 0.f; acc1[j] = 0.f; }
        gemm_pipe<38, 8, 304>((g ? Wu : Wz) + c0, X, jA, acc0, acc1);
        if (!g) {
            #pragma unroll
            for (int j = 0; j < 8; ++j) {
                int tg = tag_ids[node0 + jA + j];
                float2 tz = *(const float2*)&tag_z[tg * H + c0];
                exZ[hb][c0][j]     = sigmoidf_(acc0[j] + tz.x);
                exZ[hb][c0 + 1][j] = sigmoidf_(acc1[j] + tz.y);
            }
        }
    }
    __syncthreads();
    if (act && g) {
        float b0 = bu[c0], b1 = bu[c0 + 1];
        #pragma unroll
        for (int j = 0; j < 8; ++j) {
            float u0 = tanhf(acc0[j] + b0);
            float u1 = tanhf(acc1[j] + b1);
            float h0 = (1.f - exZ[hb][c0][j]) * u0;
            float h1 = (1.f - exZ[hb][c0 + 1][j]) * u1;
            *(float2*)&out[(long)(node0 + jA + j) * H + c0] = make_float2(h0, h1);
        }
    }
}

// Internal level, 640 threads, 16 nodes. we=0, K=600 (75 chunks).
// Per half (waves 0-4 / 5-9): phase A r|z over 8 nodes (R4 structure);
// z/S exchanged through small LDS buffers; phase B u over 4 nodes/subgroup.
__global__ __launch_bounds__(640, 3) void level16_k(
    const int* __restrict__ tag_ids,
    const float* __restrict__ Wr, const float* __restrict__ Wz,
    const float* __restrict__ Wu, const float* __restrict__ bu,
    const float* __restrict__ tag_r, const float* __restrict__ tag_z,
    float* __restrict__ out, int off, int prevOff)
{
    __shared__ float X[16][608];       // [lh|rh], scaled by r in place
    __shared__ float exS[2][300][4];   // S for local nodes 4-7 (from r-threads)
    __shared__ float exZ[2][300][4];   // z for local nodes 0-3 (from z-threads)
    int node0 = blockIdx.x * 16;
    int tid = threadIdx.x;

    for (int idx = tid; idx < 16 * 150; idx += 640) {
        int j = idx / 150, q = idx - j * 150;
        int half = q / 75, qq = q - half * 75;
        *(float4*)&X[j][half * 300 + qq * 4] =
            *(const float4*)&out[(long)(prevOff + 2 * (node0 + j) + half) * H + qq * 4];
    }
    __syncthreads();

    int hb = tid / 320;
    int tt = tid - hb * 320;
    bool act = (tt < 300);
    int g = (tt >= 150);               // 0 = r, 1 = z
    int c0 = 2 * (tt - 150 * g);
    int jA = 8 * hb;

    float acc0[8], acc1[8];
    if (act) {
        #pragma unroll
        for (int j = 0; j < 8; ++j) { acc0[j] = 0.f; acc1[j] = 0.f; }
        gemm_pipe<75, 8, 608>(((g ? Wz : Wr) + 350 * H) + c0, X, jA, acc0, acc1);
    }
    __syncthreads();   // all GEMM-A reads of X complete before in-place scale

    float vS[4][2], vZ[4][2];
    if (act) {
        if (!g) {
            #pragma unroll
            for (int j = 0; j < 8; ++j) {
                int tg = tag_ids[off + node0 + jA + j];
                float2 tr = *(const float2*)&tag_r[tg * H + c0];
                float r0 = sigmoidf_(acc0[j] + tr.x);
                float r1 = sigmoidf_(acc1[j] + tr.y);
                float l0 = X[jA + j][c0],       l1 = X[jA + j][c0 + 1];
                float q0 = X[jA + j][300 + c0], q1 = X[jA + j][300 + c0 + 1];
                float S0 = l0 + q0, S1 = l1 + q1;
                if (j < 4) { vS[j][0] = S0; vS[j][1] = S1; }
                else { exS[hb][c0][j - 4] = S0; exS[hb][c0 + 1][j - 4] = S1; }
                X[jA + j][c0] = r0 * l0;        X[jA + j][c0 + 1] = r1 * l1;
                X[jA + j][300 + c0] = r0 * q0;  X[jA + j][300 + c0 + 1] = r1 * q1;
            }
        } else {
            #pragma unroll
            for (int j = 0; j < 8; ++j) {
                int tg = tag_ids[off + node0 + jA + j];
                float2 tz = *(const float2*)&tag_z[tg * H + c0];
                float z0 = sigmoidf_(acc0[j] + tz.x);
                float z1 = sigmoidf_(acc1[j] + tz.y);
                if (j >= 4) { vZ[j - 4][0] = z0; vZ[j - 4][1] = z1; }
                else { exZ[hb][c0][j] = z0; exZ[hb][c0 + 1][j] = z1; }
            }
        }
    }
    __syncthreads();   // X scaled + exchange visible

    if (act) {
        #pragma unroll
        for (int jj = 0; jj < 4; ++jj) {
            if (!g) { vZ[jj][0] = exZ[hb][c0][jj];  vZ[jj][1] = exZ[hb][c0 + 1][jj]; }
            else    { vS[jj][0] = exS[hb][c0][jj];  vS[jj][1] = exS[hb][c0 + 1][jj]; }
        }
    }

    // Phase B: 4 subgroups x 4 nodes
    int jB = 8 * hb + 4 * g;
    float b0a[4], b1a[4];
    if (act) {
        #pragma unroll
        for (int jj = 0; jj < 4; ++jj) { b0a[jj] = 0.f; b1a[jj] = 0.f; }
        gemm_pipe<75, 4, 608>((Wu + 300 * H) + c0, X, jB, b0a, b1a);
        float bb0 = bu[c0], bb1 = bu[c0 + 1];
        #pragma unroll
        for (int jj = 0; jj < 4; ++jj) {
            float u0 = tanhf(b0a[jj] + bb0);
            float u1 = tanhf(b1a[jj] + bb1);
            float h0 = vZ[jj][0] * vS[jj][0] + (1.f - vZ[jj][0]) * u0;
            float h1 = vZ[jj][1] * vS[jj][1] + (1.f - vZ[jj][1]) * u1;
            *(float2*)&out[(long)(off + node0 + jB + jj) * H + c0] = make_float2(h0, h1);
        }
    }
}

// ---------------- Tail (m<=256): column+K-parallel, 2 kernels per level ----
__global__ __launch_bounds__(320, 1) void tail_gates_k(
    const int* __restrict__ tag_ids,
    const float* __restrict__ Wr, const float* __restrict__ Wz,
    const float* __restrict__ tag_r, const float* __restrict__ tag_z,
    const float* __restrict__ out,
    float* __restrict__ zbuf, float* __restrict__ sbuf, float* __restrict__ rxbuf,
    int off, int prevOff)
{
    __shared__ float X[608];
    __shared__ float redR[3][152];
    __shared__ float redZ[3][152];
    int n  = blockIdx.x >> 1;
    int sl = blockIdx.x & 1;
    int tid = threadIdx.x;

    for (int i = tid; i < 150; i += 320) {
        int half = i / 75, q = i - half * 75;
        *(float4*)&X[half * 300 + q * 4] =
            *(const float4*)&out[(long)(prevOff + 2 * n + half) * H + q * 4];
    }
    __syncthreads();

    int kg = tid / 75;
    int pc = tid - kg * 75;
    bool act = (tid < 300);
    int c0 = sl * 150 + 2 * pc;
    float a0r = 0.f, a1r = 0.f, a0z = 0.f, a1z = 0.f;
    if (act) {
        int ch0 = kg * 19, ch1 = (kg == 3) ? 75 : ch0 + 19;
        const float* wr = Wr + 350 * H + c0;
        const float* wz = Wz + 350 * H + c0;
        for (int ch = ch0; ch < ch1; ++ch) {
            int k = ch * 8;
            float2 wrv[8], wzv[8];
            #pragma unroll
            for (int i = 0; i < 8; ++i) {
                wrv[i] = *(const float2*)&wr[(k + i) * H];
                wzv[i] = *(const float2*)&wz[(k + i) * H];
            }
            #pragma unroll
            for (int i = 0; i < 8; ++i) {
                float xv = X[k + i];
                a0r = fmaf(xv, wrv[i].x, a0r); a1r = fmaf(xv, wrv[i].y, a1r);
                a0z = fmaf(xv, wzv[i].x, a0z); a1z = fmaf(xv, wzv[i].y, a1z);
            }
        }
        if (kg > 0) {
            redR[kg - 1][2 * pc] = a0r; redR[kg - 1][2 * pc + 1] = a1r;
            redZ[kg - 1][2 * pc] = a0z; redZ[kg - 1][2 * pc + 1] = a1z;
        }
    }
    __syncthreads();
    if (act && kg == 0) {
        a0r += redR[0][2 * pc] + redR[1][2 * pc] + redR[2][2 * pc];
        a1r += redR[0][2 * pc + 1] + redR[1][2 * pc + 1] + redR[2][2 * pc + 1];
        a0z += redZ[0][2 * pc] + redZ[1][2 * pc] + redZ[2][2 * pc];
        a1z += redZ[0][2 * pc + 1] + redZ[1][2 * pc + 1] + redZ[2][2 * pc + 1];
        int tg = tag_ids[off + n];
        float r0 = sigmoidf_(a0r + tag_r[tg * H + c0]);
        float r1 = sigmoidf_(a1r + tag_r[tg * H + c0 + 1]);
        float z0 = sigmoidf_(a0z + tag_z[tg * H + c0]);
        float z1 = sigmoidf_(a1z + tag_z[tg * H + c0 + 1]);
        float l0 = X[c0], l1 = X[c0 + 1];
        float q0 = X[300 + c0], q1 = X[300 + c0 + 1];
        *(float2*)&zbuf[n * 304 + c0]  = make_float2(z0, z1);
        *(float2*)&sbuf[n * 304 + c0]  = make_float2(l0 + q0, l1 + q1);
        *(float2*)&rxbuf[n * 608 + c0]       = make_float2(r0 * l0, r1 * l1);
        *(float2*)&rxbuf[n * 608 + 300 + c0] = make_float2(r0 * q0, r1 * q1);
    }
}

__global__ __launch_bounds__(320, 1) void tail_u_k(
    const float* __restrict__ Wu, const float* __restrict__ bu,
    const float* __restrict__ zbuf, const float* __restrict__ sbuf,
    const float* __restrict__ rxbuf,
    float* __restrict__ out, int off, float* __restrict__ dup)
{
    __shared__ float RX[608];
    __shared__ float redU[3][152];
    int n  = blockIdx.x >> 1;
    int sl = blockIdx.x & 1;
    int tid = threadIdx.x;

    for (int i = tid; i < 150; i += 320) {
        int half = i / 75, q = i - half * 75;
        *(float4*)&RX[half * 300 + q * 4] =
            *(const float4*)&rxbuf[n * 608 + half * 300 + q * 4];
    }
    __syncthreads();

    int kg = tid / 75;
    int pc = tid - kg * 75;
    bool act = (tid < 300);
    int c0 = sl * 150 + 2 * pc;
    float a0 = 0.f, a1 = 0.f;
    if (act) {
        int ch0 = kg * 19, ch1 = (kg == 3) ? 75 : ch0 + 19;
        const float* wu = Wu + 300 * H + c0;
        for (int ch = ch0; ch < ch1; ++ch) {
            int k = ch * 8;
            float2 wv[8];
            #pragma unroll
            for (int i = 0; i < 8; ++i) wv[i] = *(const float2*)&wu[(k + i) * H];
            #pragma unroll
            for (int i = 0; i < 8; ++i) {
                float xv = RX[k + i];
                a0 = fmaf(xv, wv[i].x, a0); a1 = fmaf(xv, wv[i].y, a1);
            }
        }
        if (kg > 0) { redU[kg - 1][2 * pc] = a0; redU[kg - 1][2 * pc + 1] = a1; }
    }
    __syncthreads();
    if (act && kg == 0) {
        a0 += redU[0][2 * pc] + redU[1][2 * pc] + redU[2][2 * pc];
        a1 += redU[0][2 * pc + 1] + redU[1][2 * pc + 1] + redU[2][2 * pc + 1];
        float u0 = tanhf(a0 + bu[c0]);
        float u1 = tanhf(a1 + bu[c0 + 1]);
        float z0 = zbuf[n * 304 + c0], z1 = zbuf[n * 304 + c0 + 1];
        float h0 = z0 * sbuf[n * 304 + c0]     + (1.f - z0) * u0;
        float h1 = z1 * sbuf[n * 304 + c0 + 1] + (1.f - z1) * u1;
        *(float2*)&out[(long)(off + n) * H + c0] = make_float2(h0, h1);
        if (dup && n == 0)
            *(float2*)&dup[c0] = make_float2(h0, h1);
    }
}

extern "C" void kernel_launch(void* const* d_in, const int* in_sizes, int n_in,
                              void* d_out, int out_size, void* d_ws, size_t ws_size,
                              hipStream_t stream)
{
    const int*   word_ids   = (const int*)  d_in[0];
    const int*   tag_ids    = (const int*)  d_in[1];
    const float* word_table = (const float*)d_in[2];
    const float* tag_table  = (const float*)d_in[3];
    const float* Wr         = (const float*)d_in[4];
    const float* br         = (const float*)d_in[5];
    const float* Wz         = (const float*)d_in[6];
    const float* bz         = (const float*)d_in[7];
    const float* Wu         = (const float*)d_in[8];
    const float* bu         = (const float*)d_in[9];
    float* out = (float*)d_out;

    float* tag_r = (float*)d_ws;           // 60*300
    float* tag_z = tag_r + 60 * H;         // 60*300
    float* zbuf  = tag_z + 60 * H;         // 256*304
    float* sbuf  = zbuf + 256 * 304;       // 256*304
    float* rxbuf = sbuf + 256 * 304;       // 256*608

    tag_kernel<<<60, 320, 0, stream>>>(tag_table, Wr, br, Wz, bz, tag_r, tag_z);

    leaf16_k<<<NLEAF / 16, 640, 0, stream>>>(
        word_ids, tag_ids, word_table, Wz, Wu, bu, tag_z, out);

    // Big internal levels: 640-thread blocks, 16 nodes each, 10 waves/CU.
    level16_k<<<128, 640, 0, stream>>>(tag_ids, Wr, Wz, Wu, bu, tag_r, tag_z, out, 4096, 0);
    level16_k<<<64,  640, 0, stream>>>(tag_ids, Wr, Wz, Wu, bu, tag_r, tag_z, out, 6144, 4096);
    level16_k<<<32,  640, 0, stream>>>(tag_ids, Wr, Wz, Wu, bu, tag_r, tag_z, out, 7168, 6144);

    // Tail levels m=256..1: two column+K-parallel kernels per level
    float* finalDup = out + (long)8191 * H;
    int off = 7680, prevOff = 7168;
    for (int m = 256; m >= 1; m >>= 1) {
        tail_gates_k<<<2 * m, 320, 0, stream>>>(
            tag_ids, Wr, Wz, tag_r, tag_z, out, zbuf, sbuf, rxbuf, off, prevOff);
        tail_u_k<<<2 * m, 320, 0, stream>>>(
            Wu, bu, zbuf, sbuf, rxbuf, out, off, (m == 1) ? finalDup : nullptr);
        prevOff = off;
        off += m;
    }
}

// Round 12
// 498.434 us; speedup vs baseline: 1.2594x; 1.2594x over previous
//
#include <hip/hip_runtime.h>
#include <math.h>

#define H      300
#define NLEAF  4096
#define NTHR   320

typedef unsigned int  uint;
typedef unsigned short ushort;

__device__ __forceinline__ float sigmoidf_(float x) { return 1.0f / (1.0f + expf(-x)); }

// f32 -> bf16 (RTNE), returned as ushort
__device__ __forceinline__ ushort f2bf(float f)
{
    uint u = __float_as_uint(f);
    u += 0x7FFF + ((u >> 16) & 1);
    return (ushort)(u >> 16);
}
__device__ __forceinline__ float bflo(uint u) { return __uint_as_float(u << 16); }
__device__ __forceinline__ float bfhi(uint u) { return __uint_as_float(u & 0xFFFF0000u); }

__device__ __forceinline__ void unp8(uint4 a, float* w)
{
    w[0] = bflo(a.x); w[1] = bfhi(a.x); w[2] = bflo(a.y); w[3] = bfhi(a.y);
    w[4] = bflo(a.z); w[5] = bfhi(a.z); w[6] = bflo(a.w); w[7] = bfhi(a.w);
}

// 8 k-steps x 2 cols of FMA for NN nodes; weights arrive as 2 uint4 (8 bf16/col).
template<int NN, int XW>
__device__ __forceinline__ void fma8T(uint4 a, uint4 b, const float (*X)[XW],
                                      int jbase, int d, float* a0, float* a1)
{
    float wx[8], wy[8];
    unp8(a, wx); unp8(b, wy);
    #pragma unroll
    for (int j = 0; j < NN; ++j) {
        float xv[8];
        *(float4*)&xv[0] = *(const float4*)&X[jbase + j][d];
        *(float4*)&xv[4] = *(const float4*)&X[jbase + j][d + 4];
        #pragma unroll
        for (int i = 0; i < 8; ++i) {
            a0[j] = fmaf(xv[i], wx[i], a0[j]);
            a1[j] = fmaf(xv[i], wy[i], a1[j]);
        }
    }
}

// Depth-4 software-pipelined GEMM over NCH chunks of 8 K-rows.
// p0/p1 = column-major bf16 weight columns c0 / c0+1 (contiguous in K).
template<int NCH, int NN, int XW>
__device__ __forceinline__ void gemm_pipe_T(const ushort* __restrict__ p0,
                                            const ushort* __restrict__ p1,
                                            const float (*X)[XW], int jbase,
                                            float* a0, float* a1)
{
    uint4 A0, B0, A1, B1, A2, B2, A3, B3;
    A0 = *(const uint4*)&p0[0];  B0 = *(const uint4*)&p1[0];
    A1 = *(const uint4*)&p0[8];  B1 = *(const uint4*)&p1[8];
    A2 = *(const uint4*)&p0[16]; B2 = *(const uint4*)&p1[16];
    int d = 0;
    constexpr int IT = (NCH - 3) / 4;
    constexpr int L  = (NCH - 3) - 4 * IT;
    for (int it = 0; it < IT; ++it) {
        A3 = *(const uint4*)&p0[d + 24]; B3 = *(const uint4*)&p1[d + 24];
        fma8T<NN, XW>(A0, B0, X, jbase, d, a0, a1);
        A0 = *(const uint4*)&p0[d + 32]; B0 = *(const uint4*)&p1[d + 32];
        fma8T<NN, XW>(A1, B1, X, jbase, d + 8, a0, a1);
        A1 = *(const uint4*)&p0[d + 40]; B1 = *(const uint4*)&p1[d + 40];
        fma8T<NN, XW>(A2, B2, X, jbase, d + 16, a0, a1);
        A2 = *(const uint4*)&p0[d + 48]; B2 = *(const uint4*)&p1[d + 48];
        fma8T<NN, XW>(A3, B3, X, jbase, d + 24, a0, a1);
        d += 32;
    }
    if constexpr (L == 0) {
        fma8T<NN, XW>(A0, B0, X, jbase, d,      a0, a1);
        fma8T<NN, XW>(A1, B1, X, jbase, d + 8,  a0, a1);
        fma8T<NN, XW>(A2, B2, X, jbase, d + 16, a0, a1);
    } else if constexpr (L == 1) {
        A3 = *(const uint4*)&p0[d + 24]; B3 = *(const uint4*)&p1[d + 24];
        fma8T<NN, XW>(A0, B0, X, jbase, d,      a0, a1);
        fma8T<NN, XW>(A1, B1, X, jbase, d + 8,  a0, a1);
        fma8T<NN, XW>(A2, B2, X, jbase, d + 16, a0, a1);
        fma8T<NN, XW>(A3, B3, X, jbase, d + 24, a0, a1);
    } else if constexpr (L == 2) {
        A3 = *(const uint4*)&p0[d + 24]; B3 = *(const uint4*)&p1[d + 24];
        fma8T<NN, XW>(A0, B0, X, jbase, d, a0, a1);
        A0 = *(const uint4*)&p0[d + 32]; B0 = *(const uint4*)&p1[d + 32];
        fma8T<NN, XW>(A1, B1, X, jbase, d + 8,  a0, a1);
        fma8T<NN, XW>(A2, B2, X, jbase, d + 16, a0, a1);
        fma8T<NN, XW>(A3, B3, X, jbase, d + 24, a0, a1);
        fma8T<NN, XW>(A0, B0, X, jbase, d + 32, a0, a1);
    } else {
        A3 = *(const uint4*)&p0[d + 24]; B3 = *(const uint4*)&p1[d + 24];
        fma8T<NN, XW>(A0, B0, X, jbase, d, a0, a1);
        A0 = *(const uint4*)&p0[d + 32]; B0 = *(const uint4*)&p1[d + 32];
        fma8T<NN, XW>(A1, B1, X, jbase, d + 8, a0, a1);
        A1 = *(const uint4*)&p0[d + 40]; B1 = *(const uint4*)&p1[d + 40];
        fma8T<NN, XW>(A2, B2, X, jbase, d + 16, a0, a1);
        fma8T<NN, XW>(A3, B3, X, jbase, d + 24, a0, a1);
        fma8T<NN, XW>(A0, B0, X, jbase, d + 32, a0, a1);
        fma8T<NN, XW>(A1, B1, X, jbase, d + 40, a0, a1);
    }
}

// One-time: transpose + bf16-convert the weight slices actually used.
// WrT/WzT: [300 cols][600 rows] = rows 350..950 (phase A / tail gates).
// WuT:     [300][600] = rows 300..900 (phase B / tail u).
// WzLT/WuLT: [300][304] = rows 0..304 (leaf; rows 300..303 valid memory x 0-pad).
__global__ __launch_bounds__(256) void convert_k(
    const float* __restrict__ Wr, const float* __restrict__ Wz,
    const float* __restrict__ Wu,
    ushort* __restrict__ WrT, ushort* __restrict__ WzT, ushort* __restrict__ WuT,
    ushort* __restrict__ WzLT, ushort* __restrict__ WuLT)
{
    int c = blockIdx.x;          // 0..299
    int tid = threadIdx.x;
    for (int r = tid; r < 600; r += 256) {
        WrT[c * 600 + r] = f2bf(Wr[(350 + r) * H + c]);
        WzT[c * 600 + r] = f2bf(Wz[(350 + r) * H + c]);
        WuT[c * 600 + r] = f2bf(Wu[(300 + r) * H + c]);
    }
    for (int r = tid; r < 304; r += 256) {
        WzLT[c * 304 + r] = f2bf(Wz[r * H + c]);
        WuLT[c * 304 + r] = f2bf(Wu[r * H + c]);
    }
}

// tag_r[t][k] = br[k] + sum_j tag_table[t][j] * Wr[300+j][k]  (f32, unchanged)
__global__ __launch_bounds__(320) void tag_kernel(
    const float* __restrict__ tag_table,
    const float* __restrict__ Wr, const float* __restrict__ br,
    const float* __restrict__ Wz, const float* __restrict__ bz,
    float* __restrict__ tag_r, float* __restrict__ tag_z)
{
    int t = blockIdx.x;
    int k = threadIdx.x;
    __shared__ float te[50];
    if (k < 50) te[k] = tag_table[t * 50 + k];
    __syncthreads();
    if (k < H) {
        float ar = br[k], az = bz[k];
        #pragma unroll 10
        for (int j = 0; j < 50; ++j) {
            float tv = te[j];
            ar = fmaf(tv, Wr[(H + j) * H + k], ar);
            az = fmaf(tv, Wz[(H + j) * H + k], az);
        }
        tag_r[t * H + k] = ar;
        tag_z[t * H + k] = az;
    }
}

// Leaf: lh=rh=0 => r unused; h=(1-z)*u. K padded 300->304, X pad zeroed.
template<int NB>
__global__ __launch_bounds__(NTHR, 1) void leaf_k(
    const int* __restrict__ word_ids, const int* __restrict__ tag_ids,
    const float* __restrict__ word_table,
    const ushort* __restrict__ WzLT, const ushort* __restrict__ WuLT,
    const float* __restrict__ bu, const float* __restrict__ tag_z,
    float* __restrict__ out)
{
    __shared__ float X[NB][304];
    __shared__ float Zs[NB][304];
    int node0 = blockIdx.x * NB;
    int tid = threadIdx.x;

    for (int idx = tid; idx < NB * 75; idx += NTHR) {
        int j = idx / 75, q = idx - j * 75;
        *(float4*)&X[j][q * 4] =
            *(const float4*)&word_table[(long)word_ids[node0 + j] * H + q * 4];
    }
    if (tid < NB) *(float4*)&X[tid][300] = make_float4(0.f, 0.f, 0.f, 0.f);
    __syncthreads();

    int t = tid;
    int isu = (t >= 150);
    int c0 = 2 * (t - 150 * isu);
    float acc0[NB], acc1[NB];
    if (t < 300) {
        #pragma unroll
        for (int j = 0; j < NB; ++j) { acc0[j] = 0.f; acc1[j] = 0.f; }
        const ushort* WT = isu ? WuLT : WzLT;
        gemm_pipe_T<38, NB, 304>(WT + c0 * 304, WT + (c0 + 1) * 304, X, 0, acc0, acc1);
        if (!isu) {
            #pragma unroll
            for (int j = 0; j < NB; ++j) {
                int tg = tag_ids[node0 + j];
                Zs[j][c0]     = sigmoidf_(acc0[j] + tag_z[tg * H + c0]);
                Zs[j][c0 + 1] = sigmoidf_(acc1[j] + tag_z[tg * H + c0 + 1]);
            }
        }
    }
    __syncthreads();
    if (t >= 150 && t < 300) {
        float b0 = bu[c0], b1 = bu[c0 + 1];
        #pragma unroll
        for (int j = 0; j < NB; ++j) {
            float u0 = tanhf(acc0[j] + b0);
            float u1 = tanhf(acc1[j] + b1);
            float h0 = (1.f - Zs[j][c0]) * u0;
            float h1 = (1.f - Zs[j][c0 + 1]) * u1;
            *(float2*)&out[(long)(node0 + j) * H + c0] = make_float2(h0, h1);
        }
    }
}

// Internal level (R4 structure + bf16-T weights). we=0; K=600 (75 chunks).
template<int NB>
__global__ __launch_bounds__(NTHR, 1) void level_k(
    const int* __restrict__ tag_ids,
    const ushort* __restrict__ WrT, const ushort* __restrict__ WzT,
    const ushort* __restrict__ WuT, const float* __restrict__ bu,
    const float* __restrict__ tag_r, const float* __restrict__ tag_z,
    float* __restrict__ out, int off, int prevOff)
{
    __shared__ float X[NB][608];
    __shared__ float Ss[NB][304];
    __shared__ float Zs[NB][304];
    int node0 = blockIdx.x * NB;
    int tid = threadIdx.x;

    for (int idx = tid; idx < NB * 150; idx += NTHR) {
        int j = idx / 150, q = idx - j * 150;
        int half = q / 75, qq = q - half * 75;
        *(float4*)&X[j][half * 300 + qq * 4] =
            *(const float4*)&out[(long)(prevOff + 2 * (node0 + j) + half) * H + qq * 4];
    }
    __syncthreads();

    int t = tid;
    int isz = (t >= 150);
    int c0 = 2 * (t - 150 * isz);
    float acc0[NB], acc1[NB];
    if (t < 300) {
        #pragma unroll
        for (int j = 0; j < NB; ++j) { acc0[j] = 0.f; acc1[j] = 0.f; }
        const ushort* WT = isz ? WzT : WrT;
        gemm_pipe_T<75, NB, 608>(WT + c0 * 600, WT + (c0 + 1) * 600, X, 0, acc0, acc1);
    }
    __syncthreads();   // all GEMM-A reads of X complete before in-place scale

    if (t < 300) {
        if (!isz) {
            #pragma unroll
            for (int j = 0; j < NB; ++j) {
                int tg = tag_ids[off + node0 + j];
                float r0 = sigmoidf_(acc0[j] + tag_r[tg * H + c0]);
                float r1 = sigmoidf_(acc1[j] + tag_r[tg * H + c0 + 1]);
                float l0 = X[j][c0], l1 = X[j][c0 + 1];
                float q0 = X[j][300 + c0], q1 = X[j][300 + c0 + 1];
                Ss[j][c0]     = l0 + q0;
                Ss[j][c0 + 1] = l1 + q1;
                X[j][c0]       = r0 * l0;  X[j][c0 + 1]       = r1 * l1;
                X[j][300 + c0] = r0 * q0;  X[j][300 + c0 + 1] = r1 * q1;
            }
        } else {
            #pragma unroll
            for (int j = 0; j < NB; ++j) {
                int tg = tag_ids[off + node0 + j];
                Zs[j][c0]     = sigmoidf_(acc0[j] + tag_z[tg * H + c0]);
                Zs[j][c0 + 1] = sigmoidf_(acc1[j] + tag_z[tg * H + c0 + 1]);
            }
        }
    }
    __syncthreads();

    constexpr int NBB = (NB > 1) ? NB / 2 : 1;
    int jb = (NB > 1) ? isz * NBB : 0;
    bool actB = (t < 300) && (NB > 1 || !isz);
    if (actB) {
        float b0a[NBB], b1a[NBB];
        #pragma unroll
        for (int jj = 0; jj < NBB; ++jj) { b0a[jj] = 0.f; b1a[jj] = 0.f; }
        gemm_pipe_T<75, NBB, 608>(WuT + c0 * 600, WuT + (c0 + 1) * 600, X, jb, b0a, b1a);
        float bb0 = bu[c0], bb1 = bu[c0 + 1];
        #pragma unroll
        for (int jj = 0; jj < NBB; ++jj) {
            int j = jb + jj;
            float u0 = tanhf(b0a[jj] + bb0);
            float u1 = tanhf(b1a[jj] + bb1);
            float z0 = Zs[j][c0], z1 = Zs[j][c0 + 1];
            float h0 = z0 * Ss[j][c0]     + (1.f - z0) * u0;
            float h1 = z1 * Ss[j][c0 + 1] + (1.f - z1) * u1;
            *(float2*)&out[(long)(off + node0 + j) * H + c0] = make_float2(h0, h1);
        }
    }
}

// ---------------- Tail (m<=256): column+K-parallel, 2 kernels per level ----
__global__ __launch_bounds__(320, 1) void tail_gates_k(
    const int* __restrict__ tag_ids,
    const ushort* __restrict__ WrT, const ushort* __restrict__ WzT,
    const float* __restrict__ tag_r, const float* __restrict__ tag_z,
    const float* __restrict__ out,
    float* __restrict__ zbuf, float* __restrict__ sbuf, float* __restrict__ rxbuf,
    int off, int prevOff)
{
    __shared__ float X[608];
    __shared__ float redR[3][152];
    __shared__ float redZ[3][152];
    int n  = blockIdx.x >> 1;
    int sl = blockIdx.x & 1;
    int tid = threadIdx.x;

    for (int i = tid; i < 150; i += 320) {
        int half = i / 75, q = i - half * 75;
        *(float4*)&X[half * 300 + q * 4] =
            *(const float4*)&out[(long)(prevOff + 2 * n + half) * H + q * 4];
    }
    __syncthreads();

    int kg = tid / 75;
    int pc = tid - kg * 75;
    bool act = (tid < 300);
    int c0 = sl * 150 + 2 * pc;
    float a0r = 0.f, a1r = 0.f, a0z = 0.f, a1z = 0.f;
    if (act) {
        int ch0 = kg * 19, ch1 = (kg == 3) ? 75 : ch0 + 19;
        const ushort* pr0 = WrT + c0 * 600;
        const ushort* pr1 = WrT + (c0 + 1) * 600;
        const ushort* pz0 = WzT + c0 * 600;
        const ushort* pz1 = WzT + (c0 + 1) * 600;
        for (int ch = ch0; ch < ch1; ++ch) {
            int k = ch * 8;
            uint4 ar = *(const uint4*)&pr0[k], br = *(const uint4*)&pr1[k];
            uint4 az = *(const uint4*)&pz0[k], bz = *(const uint4*)&pz1[k];
            float wrx[8], wry[8], wzx[8], wzy[8];
            unp8(ar, wrx); unp8(br, wry); unp8(az, wzx); unp8(bz, wzy);
            #pragma unroll
            for (int i = 0; i < 8; ++i) {
                float xv = X[k + i];
                a0r = fmaf(xv, wrx[i], a0r); a1r = fmaf(xv, wry[i], a1r);
                a0z = fmaf(xv, wzx[i], a0z); a1z = fmaf(xv, wzy[i], a1z);
            }
        }
        if (kg > 0) {
            redR[kg - 1][2 * pc] = a0r; redR[kg - 1][2 * pc + 1] = a1r;
            redZ[kg - 1][2 * pc] = a0z; redZ[kg - 1][2 * pc + 1] = a1z;
        }
    }
    __syncthreads();
    if (act && kg == 0) {
        a0r += redR[0][2 * pc] + redR[1][2 * pc] + redR[2][2 * pc];
        a1r += redR[0][2 * pc + 1] + redR[1][2 * pc + 1] + redR[2][2 * pc + 1];
        a0z += redZ[0][2 * pc] + redZ[1][2 * pc] + redZ[2][2 * pc];
        a1z += redZ[0][2 * pc + 1] + redZ[1][2 * pc + 1] + redZ[2][2 * pc + 1];
        int tg = tag_ids[off + n];
        float r0 = sigmoidf_(a0r + tag_r[tg * H + c0]);
        float r1 = sigmoidf_(a1r + tag_r[tg * H + c0 + 1]);
        float z0 = sigmoidf_(a0z + tag_z[tg * H + c0]);
        float z1 = sigmoidf_(a1z + tag_z[tg * H + c0 + 1]);
        float l0 = X[c0], l1 = X[c0 + 1];
        float q0 = X[300 + c0], q1 = X[300 + c0 + 1];
        *(float2*)&zbuf[n * 304 + c0]  = make_float2(z0, z1);
        *(float2*)&sbuf[n * 304 + c0]  = make_float2(l0 + q0, l1 + q1);
        *(float2*)&rxbuf[n * 608 + c0]       = make_float2(r0 * l0, r1 * l1);
        *(float2*)&rxbuf[n * 608 + 300 + c0] = make_float2(r0 * q0, r1 * q1);
    }
}

__global__ __launch_bounds__(320, 1) void tail_u_k(
    const ushort* __restrict__ WuT, const float* __restrict__ bu,
    const float* __restrict__ zbuf, const float* __restrict__ sbuf,
    const float* __restrict__ rxbuf,
    float* __restrict__ out, int off, float* __restrict__ dup)
{
    __shared__ float RX[608];
    __shared__ float redU[3][152];
    int n  = blockIdx.x >> 1;
    int sl = blockIdx.x & 1;
    int tid = threadIdx.x;

    for (int i = tid; i < 150; i += 320) {
        int half = i / 75, q = i - half * 75;
        *(float4*)&RX[half * 300 + q * 4] =
            *(const float4*)&rxbuf[n * 608 + half * 300 + q * 4];
    }
    __syncthreads();

    int kg = tid / 75;
    int pc = tid - kg * 75;
    bool act = (tid < 300);
    int c0 = sl * 150 + 2 * pc;
    float a0 = 0.f, a1 = 0.f;
    if (act) {
        int ch0 = kg * 19, ch1 = (kg == 3) ? 75 : ch0 + 19;
        const ushort* p0 = WuT + c0 * 600;
        const ushort* p1 = WuT + (c0 + 1) * 600;
        for (int ch = ch0; ch < ch1; ++ch) {
            int k = ch * 8;
            uint4 a = *(const uint4*)&p0[k], b = *(const uint4*)&p1[k];
            float wx[8], wy[8];
            unp8(a, wx); unp8(b, wy);
            #pragma unroll
            for (int i = 0; i < 8; ++i) {
                float xv = RX[k + i];
                a0 = fmaf(xv, wx[i], a0); a1 = fmaf(xv, wy[i], a1);
            }
        }
        if (kg > 0) { redU[kg - 1][2 * pc] = a0; redU[kg - 1][2 * pc + 1] = a1; }
    }
    __syncthreads();
    if (act && kg == 0) {
        a0 += redU[0][2 * pc] + redU[1][2 * pc] + redU[2][2 * pc];
        a1 += redU[0][2 * pc + 1] + redU[1][2 * pc + 1] + redU[2][2 * pc + 1];
        float u0 = tanhf(a0 + bu[c0]);
        float u1 = tanhf(a1 + bu[c0 + 1]);
        float z0 = zbuf[n * 304 + c0], z1 = zbuf[n * 304 + c0 + 1];
        float h0 = z0 * sbuf[n * 304 + c0]     + (1.f - z0) * u0;
        float h1 = z1 * sbuf[n * 304 + c0 + 1] + (1.f - z1) * u1;
        *(float2*)&out[(long)(off + n) * H + c0] = make_float2(h0, h1);
        if (dup && n == 0)
            *(float2*)&dup[c0] = make_float2(h0, h1);
    }
}

extern "C" void kernel_launch(void* const* d_in, const int* in_sizes, int n_in,
                              void* d_out, int out_size, void* d_ws, size_t ws_size,
                              hipStream_t stream)
{
    const int*   word_ids   = (const int*)  d_in[0];
    const int*   tag_ids    = (const int*)  d_in[1];
    const float* word_table = (const float*)d_in[2];
    const float* tag_table  = (const float*)d_in[3];
    const float* Wr         = (const float*)d_in[4];
    const float* br         = (const float*)d_in[5];
    const float* Wz         = (const float*)d_in[6];
    const float* bz         = (const float*)d_in[7];
    const float* Wu         = (const float*)d_in[8];
    const float* bu         = (const float*)d_in[9];
    float* out = (float*)d_out;

    float* tag_r = (float*)d_ws;           // 18000 f32
    float* tag_z = tag_r + 18000;          // 18000 f32
    float* zbuf  = tag_z + 18000;          // 256*304 f32
    float* sbuf  = zbuf + 256 * 304;       // 256*304 f32
    float* rxbuf = sbuf + 256 * 304;       // 256*608 f32
    ushort* WrT  = (ushort*)(rxbuf + 256 * 608);   // 300*600 bf16
    ushort* WzT  = WrT + 300 * 600;
    ushort* WuT  = WzT + 300 * 600;
    ushort* WzLT = WuT + 300 * 600;        // 300*304
    ushort* WuLT = WzLT + 300 * 304;

    convert_k<<<300, 256, 0, stream>>>(Wr, Wz, Wu, WrT, WzT, WuT, WzLT, WuLT);
    tag_kernel<<<60, 320, 0, stream>>>(tag_table, Wr, br, Wz, bz, tag_r, tag_z);

    leaf_k<8><<<NLEAF / 8, NTHR, 0, stream>>>(
        word_ids, tag_ids, word_table, WzLT, WuLT, bu, tag_z, out);

    level_k<8><<<256, NTHR, 0, stream>>>(tag_ids, WrT, WzT, WuT, bu, tag_r, tag_z, out, 4096, 0);
    level_k<4><<<256, NTHR, 0, stream>>>(tag_ids, WrT, WzT, WuT, bu, tag_r, tag_z, out, 6144, 4096);
    level_k<2><<<256, NTHR, 0, stream>>>(tag_ids, WrT, WzT, WuT, bu, tag_r, tag_z, out, 7168, 6144);

    // Tail levels m=256..1: two column+K-parallel kernels per level
    float* finalDup = out + (long)8191 * H;
    int off = 7680, prevOff = 7168;
    for (int m = 256; m >= 1; m >>= 1) {
        tail_gates_k<<<2 * m, 320, 0, stream>>>(
            tag_ids, WrT, WzT, tag_r, tag_z, out, zbuf, sbuf, rxbuf, off, prevOff);
        tail_u_k<<<2 * m, 320, 0, stream>>>(
            WuT, bu, zbuf, sbuf, rxbuf, out, off, (m == 1) ? finalDup : nullptr);
        prevOff = off;
        off += m;
    }
}

// Round 13
// 410.601 us; speedup vs baseline: 1.5287x; 1.2139x over previous
//
#include <hip/hip_runtime.h>
#include <math.h>

#define H 300
#define NLEAF 4096

typedef unsigned int  uint;
typedef unsigned short ushort;
typedef __attribute__((ext_vector_type(8))) short  short8;
typedef __attribute__((ext_vector_type(4))) float  f32x4;

__device__ __forceinline__ float sigmoidf_(float x) { return 1.0f / (1.0f + expf(-x)); }

__device__ __forceinline__ ushort f2bf(float f)
{
    uint u = __float_as_uint(f);
    u += 0x7FFF + ((u >> 16) & 1);
    return (ushort)(u >> 16);
}
__device__ __forceinline__ float bflo(uint u) { return __uint_as_float(u << 16); }
__device__ __forceinline__ float bfhi(uint u) { return __uint_as_float(u & 0xFFFF0000u); }
__device__ __forceinline__ uint2 pack4(float4 v)
{
    uint2 w;
    w.x = (uint)f2bf(v.x) | ((uint)f2bf(v.y) << 16);
    w.y = (uint)f2bf(v.z) | ((uint)f2bf(v.w) << 16);
    return w;
}
__device__ __forceinline__ void unp8(uint4 a, float* w)
{
    w[0] = bflo(a.x); w[1] = bfhi(a.x); w[2] = bflo(a.y); w[3] = bfhi(a.y);
    w[4] = bflo(a.z); w[5] = bfhi(a.z); w[6] = bflo(a.w); w[7] = bfhi(a.w);
}

// ---- per-wave MFMA GEMM: NT 16-wide col-tiles, KSTEPS k-steps of 32 ----
// A in LDS (row stride AS ushorts, 16 rows). B global col-major (col stride KS).
// Fragment layout (guide §3): A row=lane%16, k=(lane>>4)*8+i; B col=lane%16;
// C/D col=lane&15, row=(lane>>4)*4+reg (m89-verified).
template<int NT, int KSTEPS, int AS, int KS>
__device__ __forceinline__ void mfma_gemm(const ushort* A_lds, const ushort* __restrict__ B,
                                          int colT0, int lane, f32x4* acc)
{
    const ushort* Ap = A_lds + (lane & 15) * AS + ((lane >> 4) * 8);
    const ushort* Bp[NT];
    #pragma unroll
    for (int t = 0; t < NT; ++t)
        Bp[t] = B + (long)(colT0 + 16 * t + (lane & 15)) * KS + ((lane >> 4) * 8);

    short8 aA, aB, bA[NT], bB[NT];
    aA = *(const short8*)Ap;
    #pragma unroll
    for (int t = 0; t < NT; ++t) bA[t] = *(const short8*)Bp[t];

    int s = 0;
    #pragma unroll 1
    for (; s + 2 < KSTEPS; s += 2) {
        aB = *(const short8*)(Ap + (s + 1) * 32);
        #pragma unroll
        for (int t = 0; t < NT; ++t) bB[t] = *(const short8*)(Bp[t] + (s + 1) * 32);
        #pragma unroll
        for (int t = 0; t < NT; ++t)
            acc[t] = __builtin_amdgcn_mfma_f32_16x16x32_bf16(aA, bA[t], acc[t], 0, 0, 0);
        aA = *(const short8*)(Ap + (s + 2) * 32);
        #pragma unroll
        for (int t = 0; t < NT; ++t) bA[t] = *(const short8*)(Bp[t] + (s + 2) * 32);
        #pragma unroll
        for (int t = 0; t < NT; ++t)
            acc[t] = __builtin_amdgcn_mfma_f32_16x16x32_bf16(aB, bB[t], acc[t], 0, 0, 0);
    }
    if (KSTEPS - s == 2) {
        aB = *(const short8*)(Ap + (s + 1) * 32);
        #pragma unroll
        for (int t = 0; t < NT; ++t) bB[t] = *(const short8*)(Bp[t] + (s + 1) * 32);
        #pragma unroll
        for (int t = 0; t < NT; ++t)
            acc[t] = __builtin_amdgcn_mfma_f32_16x16x32_bf16(aA, bA[t], acc[t], 0, 0, 0);
        #pragma unroll
        for (int t = 0; t < NT; ++t)
            acc[t] = __builtin_amdgcn_mfma_f32_16x16x32_bf16(aB, bB[t], acc[t], 0, 0, 0);
    } else {
        #pragma unroll
        for (int t = 0; t < NT; ++t)
            acc[t] = __builtin_amdgcn_mfma_f32_16x16x32_bf16(aA, bA[t], acc[t], 0, 0, 0);
    }
}

// ---- one-time weight transpose+convert to bf16, K padded per-half to 304 ----
// WArz [640 cols][608]: cols 0-299 r (Wr rows 350-649 | 0x4 | 650-949 | 0x4),
//   300-319 zero, 320-619 z (Wz same), 620-639 zero.
// WuTp [320][608]: Wu rows 300-599 | 0 | 600-899 | 0.
// WLzu [640][320]: cols 0-299 Wz rows 0-299 (+20 zero rows), 320-619 Wu.
__global__ __launch_bounds__(256) void convert_k(
    const float* __restrict__ Wr, const float* __restrict__ Wz,
    const float* __restrict__ Wu,
    ushort* __restrict__ WArz, ushort* __restrict__ WuTp, ushort* __restrict__ WLzu)
{
    int c = blockIdx.x;          // 0..639
    int tid = threadIdx.x;
    int gate = (c >= 320);
    int cc = gate ? c - 320 : c;
    const float* WA = gate ? Wz : Wr;
    for (int r = tid; r < 608; r += 256) {
        float v = 0.f;
        if (cc < 300) {
            if (r < 300) v = WA[(350 + r) * H + cc];
            else if (r >= 304 && r < 604) v = WA[(r + 346) * H + cc];
        }
        WArz[(long)c * 608 + r] = f2bf(v);
    }
    const float* WL = gate ? Wu : Wz;
    for (int r = tid; r < 320; r += 256) {
        float v = (cc < 300 && r < 300) ? WL[r * H + cc] : 0.f;
        WLzu[(long)c * 320 + r] = f2bf(v);
    }
    if (c < 320) {
        for (int r = tid; r < 608; r += 256) {
            float v = 0.f;
            if (c < 300) {
                if (r < 300) v = Wu[(300 + r) * H + c];
                else if (r >= 304 && r < 604) v = Wu[(r + 296) * H + c];
            }
            WuTp[(long)c * 608 + r] = f2bf(v);
        }
    }
}

// tag_r[t][k] = br[k] + sum_j tag_table[t][j]*Wr[300+j][k]  (likewise tag_z)
__global__ __launch_bounds__(320) void tag_kernel(
    const float* __restrict__ tag_table,
    const float* __restrict__ Wr, const float* __restrict__ br,
    const float* __restrict__ Wz, const float* __restrict__ bz,
    float* __restrict__ tag_r, float* __restrict__ tag_z)
{
    int t = blockIdx.x;
    int k = threadIdx.x;
    __shared__ float te[50];
    if (k < 50) te[k] = tag_table[t * 50 + k];
    __syncthreads();
    if (k < H) {
        float ar = br[k], az = bz[k];
        #pragma unroll 10
        for (int j = 0; j < 50; ++j) {
            float tv = te[j];
            ar = fmaf(tv, Wr[(H + j) * H + k], ar);
            az = fmaf(tv, Wz[(H + j) * H + k], az);
        }
        tag_r[t * H + k] = ar;
        tag_z[t * H + k] = az;
    }
}

// ---- Leaf (MFMA): M-tile 16 nodes, N=640 (z cols 0-319, u 320-639), K=320.
__global__ __launch_bounds__(256, 1) void leaf_mfma_k(
    const int* __restrict__ word_ids, const int* __restrict__ tag_ids,
    const float* __restrict__ word_table, const ushort* __restrict__ WLzu,
    const float* __restrict__ bu, const float* __restrict__ tag_z,
    float* __restrict__ out)
{
    __shared__ ushort Abf[16 * 328];     // 16 rows x (320 + 8 pad)
    __shared__ float  zL[16][304];
    int tid = threadIdx.x;
    int node0 = blockIdx.x * 16;

    for (int idx = tid; idx < 16 * 82; idx += 256) {
        int j = idx / 82, q = idx - j * 82;
        char* rowb = (char*)(Abf + j * 328);
        if (q < 75) {
            float4 v = ((const float4*)(word_table + (long)word_ids[node0 + j] * H))[q];
            *(uint2*)(rowb + q * 8) = pack4(v);
        } else {
            *(uint2*)(rowb + q * 8) = make_uint2(0u, 0u);   // bytes 600..655
        }
    }
    __syncthreads();

    int wv = tid >> 6, lane = tid & 63;
    int jrow = (lane >> 4) * 4;
    int tg[4];
    #pragma unroll
    for (int q = 0; q < 4; ++q) tg[q] = tag_ids[node0 + jrow + q];

    f32x4 acc[5];
    #pragma unroll
    for (int t = 0; t < 5; ++t) acc[t] = (f32x4)(0.f);
    int colT0 = wv * 80;                       // z tiles
    mfma_gemm<5, 10, 328, 320>(Abf, WLzu, colT0, lane, acc);
    #pragma unroll
    for (int t = 0; t < 5; ++t) {
        int c = colT0 + t * 16 + (lane & 15);
        #pragma unroll
        for (int q = 0; q < 4; ++q)
            if (c < 300) zL[jrow + q][c] = sigmoidf_(acc[t][q] + tag_z[tg[q] * H + c]);
    }
    __syncthreads();

    #pragma unroll
    for (int t = 0; t < 5; ++t) acc[t] = (f32x4)(0.f);
    int colT0u = 320 + wv * 80;                // u tiles
    mfma_gemm<5, 10, 328, 320>(Abf, WLzu, colT0u, lane, acc);
    #pragma unroll
    for (int t = 0; t < 5; ++t) {
        int c = colT0u - 320 + t * 16 + (lane & 15);
        #pragma unroll
        for (int q = 0; q < 4; ++q) {
            if (c < 300) {
                int jn = jrow + q;
                float u = tanhf(acc[t][q] + bu[c]);
                float z = zL[jn][c];
                out[(long)(node0 + jn) * H + c] = (1.f - z) * u;
            }
        }
    }
}

// ---- Internal level kernel A (gates): C[m x 640] = X[m x 608] * WArz.
// Block: 16 nodes x 320 cols (nb selects r- or z-half). Epilogue r-half:
// S=lh+rh (f32 from out), rx=[r*lh|r*rh] -> rxbf bf16. z-half: zws f32.
__global__ __launch_bounds__(256, 1) void gates_mfma_k(
    const int* __restrict__ tag_ids, const ushort* __restrict__ WArz,
    const float* __restrict__ tag_r, const float* __restrict__ tag_z,
    const float* __restrict__ out,
    float* __restrict__ zws, float* __restrict__ Sws, ushort* __restrict__ rxbf,
    int off, int prevOff)
{
    __shared__ ushort Abf[16 * 616];     // 16 x (608 + 8 pad)
    int tid = threadIdx.x;
    int mb = blockIdx.x >> 1, nb = blockIdx.x & 1;
    int node0 = mb * 16;

    for (int idx = tid; idx < 16 * 154; idx += 256) {
        int j = idx / 154, q = idx - j * 154;
        char* rowb = (char*)(Abf + j * 616);
        if (q < 75) {
            float4 v = ((const float4*)(out + (long)(prevOff + 2 * (node0 + j)) * H))[q];
            *(uint2*)(rowb + q * 8) = pack4(v);
        } else if (q < 150) {
            int qq = q - 75;
            float4 v = ((const float4*)(out + (long)(prevOff + 2 * (node0 + j) + 1) * H))[qq];
            *(uint2*)(rowb + 608 + qq * 8) = pack4(v);
        } else {
            int pb = (q == 150) ? 600 : (1208 + (q - 151) * 8);   // pads 300-303, 604-615
            *(uint2*)(rowb + pb) = make_uint2(0u, 0u);
        }
    }
    __syncthreads();

    int wv = tid >> 6, lane = tid & 63;
    f32x4 acc[5];
    #pragma unroll
    for (int t = 0; t < 5; ++t) acc[t] = (f32x4)(0.f);
    int colT0 = nb * 320 + wv * 80;
    mfma_gemm<5, 19, 616, 608>(Abf, WArz, colT0, lane, acc);

    int jrow = (lane >> 4) * 4;
    int tg[4];
    #pragma unroll
    for (int q = 0; q < 4; ++q) tg[q] = tag_ids[off + node0 + jrow + q];

    #pragma unroll
    for (int t = 0; t < 5; ++t) {
        int c = colT0 - nb * 320 + t * 16 + (lane & 15);   // gate-local col 0..319
        #pragma unroll
        for (int q = 0; q < 4; ++q) {
            int jn = jrow + q;
            float av = acc[t][q];
            if (nb == 0) {
                if (c < 300) {
                    float r  = sigmoidf_(av + tag_r[tg[q] * H + c]);
                    float lh = out[(long)(prevOff + 2 * (node0 + jn)) * H + c];
                    float rh = out[(long)(prevOff + 2 * (node0 + jn) + 1) * H + c];
                    Sws[(node0 + jn) * 304 + c] = lh + rh;
                    rxbf[(long)(node0 + jn) * 608 + c]       = f2bf(r * lh);
                    rxbf[(long)(node0 + jn) * 608 + 304 + c] = f2bf(r * rh);
                } else if (c < 304) {
                    rxbf[(long)(node0 + jn) * 608 + c]       = 0;
                    rxbf[(long)(node0 + jn) * 608 + 304 + c] = 0;
                }
            } else {
                if (c < 300)
                    zws[(node0 + jn) * 304 + c] = sigmoidf_(av + tag_z[tg[q] * H + c]);
            }
        }
    }
}

// ---- Internal level kernel B (u + combine): U = rxbf[m x 608] * WuTp[608 x 320]
__global__ __launch_bounds__(256, 1) void u_mfma_k(
    const ushort* __restrict__ WuTp, const float* __restrict__ bu,
    const float* __restrict__ zws, const float* __restrict__ Sws,
    const ushort* __restrict__ rxbf, float* __restrict__ out, int off)
{
    __shared__ ushort Abf[16 * 616];
    int tid = threadIdx.x;
    int node0 = blockIdx.x * 16;

    for (int idx = tid; idx < 16 * 77; idx += 256) {
        int j = idx / 77, q = idx - j * 77;
        uint4* dst = (uint4*)(Abf + j * 616) + q;
        if (q < 76) *dst = ((const uint4*)(rxbf + (long)(node0 + j) * 608))[q];
        else        *dst = make_uint4(0u, 0u, 0u, 0u);
    }
    __syncthreads();

    int wv = tid >> 6, lane = tid & 63;
    f32x4 acc[5];
    #pragma unroll
    for (int t = 0; t < 5; ++t) acc[t] = (f32x4)(0.f);
    int colT0 = wv * 80;
    mfma_gemm<5, 19, 616, 608>(Abf, WuTp, colT0, lane, acc);

    int jrow = (lane >> 4) * 4;
    #pragma unroll
    for (int t = 0; t < 5; ++t) {
        int c = colT0 + t * 16 + (lane & 15);
        #pragma unroll
        for (int q = 0; q < 4; ++q) {
            if (c < 300) {
                int jn = jrow + q;
                float u = tanhf(acc[t][q] + bu[c]);
                float z = zws[(node0 + jn) * 304 + c];
                float S = Sws[(node0 + jn) * 304 + c];
                out[(long)(off + node0 + jn) * H + c] = z * S + (1.f - z) * u;
            }
        }
    }
}

// ---------------- Tail (m<=256): column+K-parallel VALU, bf16-T weights ----
__global__ __launch_bounds__(320, 1) void tail_gates_k(
    const int* __restrict__ tag_ids, const ushort* __restrict__ WArz,
    const float* __restrict__ tag_r, const float* __restrict__ tag_z,
    const float* __restrict__ out,
    float* __restrict__ zbuf, float* __restrict__ sbuf, float* __restrict__ rxbuf,
    int off, int prevOff)
{
    __shared__ float X[608];
    __shared__ float redR[3][152];
    __shared__ float redZ[3][152];
    int n  = blockIdx.x >> 1;
    int sl = blockIdx.x & 1;
    int tid = threadIdx.x;

    for (int i = tid; i < 152; i += 320) {
        if (i < 75)
            *(float4*)&X[i * 4] = ((const float4*)(out + (long)(prevOff + 2 * n) * H))[i];
        else if (i < 150)
            *(float4*)&X[304 + (i - 75) * 4] =
                ((const float4*)(out + (long)(prevOff + 2 * n + 1) * H))[i - 75];
        else if (i == 150) { X[300] = X[301] = X[302] = X[303] = 0.f; }
        else { X[604] = X[605] = X[606] = X[607] = 0.f; }
    }
    __syncthreads();

    int kg = tid / 75;
    int pc = tid - kg * 75;
    bool act = (tid < 300);
    int c0 = sl * 150 + 2 * pc;
    float a0r = 0.f, a1r = 0.f, a0z = 0.f, a1z = 0.f;
    if (act) {
        int ch0 = kg * 19, ch1 = ch0 + 19;         // 76 chunks of 8 over K=608
        const ushort* pr0 = WArz + (long)c0 * 608;
        const ushort* pr1 = WArz + (long)(c0 + 1) * 608;
        const ushort* pz0 = WArz + (long)(320 + c0) * 608;
        const ushort* pz1 = WArz + (long)(321 + c0) * 608;
        for (int ch = ch0; ch < ch1; ++ch) {
            int k = ch * 8;
            uint4 ar = *(const uint4*)&pr0[k], br = *(const uint4*)&pr1[k];
            uint4 az = *(const uint4*)&pz0[k], bz = *(const uint4*)&pz1[k];
            float wrx[8], wry[8], wzx[8], wzy[8];
            unp8(ar, wrx); unp8(br, wry); unp8(az, wzx); unp8(bz, wzy);
            #pragma unroll
            for (int i = 0; i < 8; ++i) {
                float xv = X[k + i];
                a0r = fmaf(xv, wrx[i], a0r); a1r = fmaf(xv, wry[i], a1r);
                a0z = fmaf(xv, wzx[i], a0z); a1z = fmaf(xv, wzy[i], a1z);
            }
        }
        if (kg > 0) {
            redR[kg - 1][2 * pc] = a0r; redR[kg - 1][2 * pc + 1] = a1r;
            redZ[kg - 1][2 * pc] = a0z; redZ[kg - 1][2 * pc + 1] = a1z;
        }
    }
    __syncthreads();
    if (act && kg == 0) {
        a0r += redR[0][2 * pc] + redR[1][2 * pc] + redR[2][2 * pc];
        a1r += redR[0][2 * pc + 1] + redR[1][2 * pc + 1] + redR[2][2 * pc + 1];
        a0z += redZ[0][2 * pc] + redZ[1][2 * pc] + redZ[2][2 * pc];
        a1z += redZ[0][2 * pc + 1] + redZ[1][2 * pc + 1] + redZ[2][2 * pc + 1];
        int tg = tag_ids[off + n];
        float r0 = sigmoidf_(a0r + tag_r[tg * H + c0]);
        float r1 = sigmoidf_(a1r + tag_r[tg * H + c0 + 1]);
        float z0 = sigmoidf_(a0z + tag_z[tg * H + c0]);
        float z1 = sigmoidf_(a1z + tag_z[tg * H + c0 + 1]);
        float l0 = X[c0], l1 = X[c0 + 1];
        float q0 = X[304 + c0], q1 = X[304 + c0 + 1];
        *(float2*)&zbuf[n * 304 + c0] = make_float2(z0, z1);
        *(float2*)&sbuf[n * 304 + c0] = make_float2(l0 + q0, l1 + q1);
        *(float2*)&rxbuf[n * 608 + c0]       = make_float2(r0 * l0, r1 * l1);
        *(float2*)&rxbuf[n * 608 + 304 + c0] = make_float2(r0 * q0, r1 * q1);
        if (sl == 1 && pc == 0) {
            *(float4*)&rxbuf[n * 608 + 300] = make_float4(0.f, 0.f, 0.f, 0.f);
            *(float4*)&rxbuf[n * 608 + 604] = make_float4(0.f, 0.f, 0.f, 0.f);
        }
    }
}

__global__ __launch_bounds__(320, 1) void tail_u_k(
    const ushort* __restrict__ WuTp, const float* __restrict__ bu,
    const float* __restrict__ zbuf, const float* __restrict__ sbuf,
    const float* __restrict__ rxbuf,
    float* __restrict__ out, int off, float* __restrict__ dup)
{
    __shared__ float RX[608];
    __shared__ float redU[3][152];
    int n  = blockIdx.x >> 1;
    int sl = blockIdx.x & 1;
    int tid = threadIdx.x;

    for (int i = tid; i < 152; i += 320)
        ((float4*)RX)[i] = ((const float4*)(rxbuf + n * 608))[i];
    __syncthreads();

    int kg = tid / 75;
    int pc = tid - kg * 75;
    bool act = (tid < 300);
    int c0 = sl * 150 + 2 * pc;
    float a0 = 0.f, a1 = 0.f;
    if (act) {
        int ch0 = kg * 19, ch1 = ch0 + 19;
        const ushort* p0 = WuTp + (long)c0 * 608;
        const ushort* p1 = WuTp + (long)(c0 + 1) * 608;
        for (int ch = ch0; ch < ch1; ++ch) {
            int k = ch * 8;
            uint4 a = *(const uint4*)&p0[k], b = *(const uint4*)&p1[k];
            float wx[8], wy[8];
            unp8(a, wx); unp8(b, wy);
            #pragma unroll
            for (int i = 0; i < 8; ++i) {
                float xv = RX[k + i];
                a0 = fmaf(xv, wx[i], a0); a1 = fmaf(xv, wy[i], a1);
            }
        }
        if (kg > 0) { redU[kg - 1][2 * pc] = a0; redU[kg - 1][2 * pc + 1] = a1; }
    }
    __syncthreads();
    if (act && kg == 0) {
        a0 += redU[0][2 * pc] + redU[1][2 * pc] + redU[2][2 * pc];
        a1 += redU[0][2 * pc + 1] + redU[1][2 * pc + 1] + redU[2][2 * pc + 1];
        float u0 = tanhf(a0 + bu[c0]);
        float u1 = tanhf(a1 + bu[c0 + 1]);
        float z0 = zbuf[n * 304 + c0], z1 = zbuf[n * 304 + c0 + 1];
        float h0 = z0 * sbuf[n * 304 + c0]     + (1.f - z0) * u0;
        float h1 = z1 * sbuf[n * 304 + c0 + 1] + (1.f - z1) * u1;
        *(float2*)&out[(long)(off + n) * H + c0] = make_float2(h0, h1);
        if (dup && n == 0)
            *(float2*)&dup[c0] = make_float2(h0, h1);
    }
}

extern "C" void kernel_launch(void* const* d_in, const int* in_sizes, int n_in,
                              void* d_out, int out_size, void* d_ws, size_t ws_size,
                              hipStream_t stream)
{
    const int*   word_ids   = (const int*)  d_in[0];
    const int*   tag_ids    = (const int*)  d_in[1];
    const float* word_table = (const float*)d_in[2];
    const float* tag_table  = (const float*)d_in[3];
    const float* Wr         = (const float*)d_in[4];
    const float* br         = (const float*)d_in[5];
    const float* Wz         = (const float*)d_in[6];
    const float* bz         = (const float*)d_in[7];
    const float* Wu         = (const float*)d_in[8];
    const float* bu         = (const float*)d_in[9];
    float* out = (float*)d_out;

    float* tag_r = (float*)d_ws;                 // 18000
    float* tag_z = tag_r + 18000;                // 18000
    float* zws   = tag_z + 18000;                // 2048*304
    float* Sws   = zws + 2048 * 304;             // 2048*304
    float* trx   = Sws + 2048 * 304;             // 256*608 (tail rx, f32)
    ushort* rxbf = (ushort*)(trx + 256 * 608);   // 2048*608 bf16
    ushort* WArz = rxbf + 2048L * 608;           // 640*608
    ushort* WuTp = WArz + 640L * 608;            // 320*608
    ushort* WLzu = WuTp + 320L * 608;            // 640*320

    convert_k<<<640, 256, 0, stream>>>(Wr, Wz, Wu, WArz, WuTp, WLzu);
    tag_kernel<<<60, 320, 0, stream>>>(tag_table, Wr, br, Wz, bz, tag_r, tag_z);

    leaf_mfma_k<<<NLEAF / 16, 256, 0, stream>>>(
        word_ids, tag_ids, word_table, WLzu, bu, tag_z, out);

    // Big internal levels: gates GEMM + u GEMM (MFMA)
    int off = NLEAF, prevOff = 0;
    for (int m = 2048; m >= 512; m >>= 1) {
        gates_mfma_k<<<(m / 16) * 2, 256, 0, stream>>>(
            tag_ids, WArz, tag_r, tag_z, out, zws, Sws, rxbf, off, prevOff);
        u_mfma_k<<<m / 16, 256, 0, stream>>>(WuTp, bu, zws, Sws, rxbf, out, off);
        prevOff = off;
        off += m;
    }

    // Tail levels m=256..1 (VALU, bf16 weights)
    float* finalDup = out + (long)8191 * H;
    for (int m = 256; m >= 1; m >>= 1) {
        tail_gates_k<<<2 * m, 320, 0, stream>>>(
            tag_ids, WArz, tag_r, tag_z, out, zws, Sws, trx, off, prevOff);
        tail_u_k<<<2 * m, 320, 0, stream>>>(
            WuTp, bu, zws, Sws, trx, out, off, (m == 1) ? finalDup : nullptr);
        prevOff = off;
        off += m;
    }
}